// Round 6
// baseline (790.149 us; speedup 1.0000x reference)
//
#include <hip/hip_runtime.h>
#include <math.h>

#define HH 180
#define WW 240
#define T_AGGC 3
#define NBC 4
#define BBC (NBC * T_AGGC)          // 12
#define M_EVC 32
#define ROWS (BBC * 2 * HH * WW)    // 1,036,800
#define MLPH 20
#define RNNH 20
#define LRELU_SLOPE 0.1f
#define HPAD 21                     // per-thread h stride in LDS
#define TBL 65536                   // F(v0) table entries

__device__ __forceinline__ float lrelu(float x) { return x > 0.0f ? x : LRELU_SLOPE * x; }
__device__ __forceinline__ float sigm(float x)  { return 1.0f / (1.0f + __expf(-x)); }
__device__ __forceinline__ float ftanh(float x) { return 1.0f - 2.0f / (__expf(2.0f * x) + 1.0f); }

// order-preserving float<->uint for atomic min/max
__device__ __forceinline__ unsigned fenc(float f) {
    unsigned u = __float_as_uint(f);
    return (u & 0x80000000u) ? ~u : (u | 0x80000000u);
}
__device__ __forceinline__ float fdec(unsigned k) {
    unsigned u = (k & 0x80000000u) ? (k & 0x7fffffffu) : ~k;
    return __uint_as_float(u);
}

__global__ void init_range(unsigned* __restrict__ vr) {
    vr[0] = 0xFFFFFFFFu;   // min slot (encoded)
    vr[1] = 0u;            // max slot (encoded)
}

// ---------------- Kernel 1: per-event MLP + scatter (+ value min/max) ----------------
__global__ __launch_bounds__(256) void ev_mlp_scatter(
    const float* __restrict__ ev, int n,
    const float* __restrict__ W1, const float* __restrict__ b1,
    const float* __restrict__ W2, const float* __restrict__ b2,
    const float* __restrict__ W3, const float* __restrict__ b3,
    float* __restrict__ vox, unsigned int* __restrict__ mask,
    float* __restrict__ rsum, float* __restrict__ v0out,
    unsigned* __restrict__ vr, int do_minmax)
{
    __shared__ __align__(16) float sW2[MLPH * MLPH];
    __shared__ float sW1[MLPH], sb1[MLPH], sb2[MLPH], sW3[MLPH];
    __shared__ float sb3;
    int tid = threadIdx.x;
    for (int i = tid; i < MLPH * MLPH; i += blockDim.x) sW2[i] = W2[i];
    if (tid < MLPH) { sW1[tid] = W1[tid]; sb1[tid] = b1[tid]; sb2[tid] = b2[tid]; sW3[tid] = W3[tid]; }
    if (tid == 0) sb3 = b3[0];
    __syncthreads();

    int i = blockIdx.x * blockDim.x + tid;
    bool act = (i < n);
    float val = 0.0f;

    if (act) {
        const float* e = ev + (size_t)i * 7;
        float t = e[3];

        float h1[MLPH];
#pragma unroll
        for (int k = 0; k < MLPH; k++) h1[k] = lrelu(fmaf(t, sW1[k], sb1[k]));

        val = sb3;
#pragma unroll
        for (int j = 0; j < MLPH; j++) {
            float a = sb2[j];
            const float4* wr = (const float4*)&sW2[j * MLPH];
#pragma unroll
            for (int k4 = 0; k4 < MLPH / 4; k4++) {
                float4 w = wr[k4];
                a = fmaf(h1[k4 * 4 + 0], w.x, a);
                a = fmaf(h1[k4 * 4 + 1], w.y, a);
                a = fmaf(h1[k4 * 4 + 2], w.z, a);
                a = fmaf(h1[k4 * 4 + 3], w.w, a);
            }
            val = fmaf(lrelu(a), sW3[j], val);
        }

        int xi = (int)e[0], yi = (int)e[1], pi = (int)e[2];
        int ipi = (int)e[4], ti = (int)e[5], bi = (int)e[6];
        int row = xi + WW * yi + WW * HH * pi + 2 * WW * HH * (bi * T_AGGC + ti);
        int pos = ipi - 1;
        vox[(size_t)row * M_EVC + pos] = val;
        if (pos == 0) v0out[row] = val;          // v0 fast-path stash (d_out; overwritten by kernel 2)
        if (val != 0.0f) {                       // matches (vox != 0) semantics
            atomicOr(&mask[row], 1u << pos);
            atomicAdd(&rsum[row], val);
        }
    }

    if (do_minmax) {
        unsigned kmin = act ? fenc(val) : 0xFFFFFFFFu;
        unsigned kmax = act ? fenc(val) : 0u;
#pragma unroll
        for (int off = 32; off; off >>= 1) {
            unsigned omin = (unsigned)__shfl_xor((int)kmin, off);
            unsigned omax = (unsigned)__shfl_xor((int)kmax, off);
            kmin = omin < kmin ? omin : kmin;
            kmax = omax > kmax ? omax : kmax;
        }
        if ((tid & 63) == 0) {
            atomicMin(&vr[0], kmin);
            atomicMax(&vr[1], kmax);
        }
    }
}

// ---------------- Table kernel: F(v) = out of {step0(v); one x=0 step; W2-projection} ----------------
__global__ __launch_bounds__(256) void build_table(
    const float* __restrict__ rW1, const float* __restrict__ rb1,
    const float* __restrict__ Wih, const float* __restrict__ Whh,
    const float* __restrict__ bih, const float* __restrict__ bhh,
    const float* __restrict__ rW2, const float* __restrict__ rb2,
    const unsigned* __restrict__ vr, float* __restrict__ table)
{
    __shared__ __align__(16) float sW[4 * RNNH * RNNH];      // Whh row-major (rows of 20 = 80B, 16B-aligned)
    __shared__ __align__(16) float sA[4 * RNNH], sC[4 * RNNH];
    __shared__ float sW2r[RNNH];
    __shared__ float sb2o;
    int tid = threadIdx.x;
    for (int i = tid; i < 4 * RNNH * RNNH; i += blockDim.x) sW[i] = Whh[i];
    if (tid < 4 * RNNH) {
        float a = 0.0f, cc = bih[tid] + bhh[tid];
        for (int k = 0; k < RNNH; k++) {
            float w = Wih[tid * RNNH + k];
            a = fmaf(rW1[k], w, a);
            cc = fmaf(rb1[k], w, cc);
        }
        sA[tid] = a; sC[tid] = cc;
    }
    if (tid < RNNH) sW2r[tid] = rW2[tid];
    if (tid == 0) sb2o = rb2[0];
    __syncthreads();

    int i = blockIdx.x * blockDim.x + tid;
    float vmin = fdec(vr[0]), vmax = fdec(vr[1]);
    float v = vmin + (vmax - vmin) * (1.0f / (TBL - 1)) * (float)i;

    // step 0 (h=c=0)
    float h0[RNNH], c1[RNNH];
#pragma unroll
    for (int u = 0; u < RNNH; u++) {
        float gi = fmaf(v, sA[u],            sC[u]);
        float gg = fmaf(v, sA[u + 2 * RNNH], sC[u + 2 * RNNH]);
        float go = fmaf(v, sA[u + 3 * RNNH], sC[u + 3 * RNNH]);
        float cn = sigm(gi) * ftanh(gg);
        c1[u] = cn;
        h0[u] = sigm(go) * ftanh(cn);
    }

    // step 1 with x = 0: gates = C + h0 @ Whh^T
    float oacc = sb2o;
#pragma unroll
    for (int u = 0; u < RNNH; u++) {
        float gi = sC[u], gf = sC[u + RNNH], gg = sC[u + 2 * RNNH], go = sC[u + 3 * RNNH];
        const float4* wi = (const float4*)&sW[u * RNNH];
        const float4* wf = (const float4*)&sW[(u + RNNH) * RNNH];
        const float4* wg = (const float4*)&sW[(u + 2 * RNNH) * RNNH];
        const float4* wo = (const float4*)&sW[(u + 3 * RNNH) * RNNH];
#pragma unroll
        for (int q = 0; q < 5; q++) {
            float4 a = wi[q], b = wf[q], cq = wg[q], d = wo[q];
            gi = fmaf(h0[4*q+0], a.x, gi); gi = fmaf(h0[4*q+1], a.y, gi);
            gi = fmaf(h0[4*q+2], a.z, gi); gi = fmaf(h0[4*q+3], a.w, gi);
            gf = fmaf(h0[4*q+0], b.x, gf); gf = fmaf(h0[4*q+1], b.y, gf);
            gf = fmaf(h0[4*q+2], b.z, gf); gf = fmaf(h0[4*q+3], b.w, gf);
            gg = fmaf(h0[4*q+0], cq.x, gg); gg = fmaf(h0[4*q+1], cq.y, gg);
            gg = fmaf(h0[4*q+2], cq.z, gg); gg = fmaf(h0[4*q+3], cq.w, gg);
            go = fmaf(h0[4*q+0], d.x, go); go = fmaf(h0[4*q+1], d.y, go);
            go = fmaf(h0[4*q+2], d.z, go); go = fmaf(h0[4*q+3], d.w, go);
        }
        float c2 = fmaf(sigm(gf), c1[u], sigm(gi) * ftanh(gg));
        oacc = fmaf(sigm(go) * ftanh(c2), sW2r[u], oacc);
    }
    table[i] = oacc;
}

// ---------------- Kernel 2: per-row output (table fast path + general LSTM fallback) ----------------
__global__ __launch_bounds__(256) void row_out(
    const unsigned int* __restrict__ mask, const float* __restrict__ rsum,
    const float* __restrict__ vox,
    const float* __restrict__ rW1, const float* __restrict__ rb1,
    const float* __restrict__ Wih, const float* __restrict__ Whh,
    const float* __restrict__ bih, const float* __restrict__ bhh,
    const float* __restrict__ rW2, const float* __restrict__ rb2,
    const float* __restrict__ table, const unsigned* __restrict__ vr,
    int use_table, float* __restrict__ out)
{
    __shared__ __align__(16) float sW1t[RNNH][2 * RNNH];  // [k][0..19]=i, [20..39]=g
    __shared__ __align__(16) float sW2t[RNNH][2 * RNNH];  // [k][0..19]=f, [20..39]=o
    __shared__ __align__(16) float sA[4 * RNNH], sC[4 * RNNH];
    __shared__ float sW2r[RNNH];
    __shared__ float sb2o;
    __shared__ float sH[256 * HPAD];

    int tid = threadIdx.x;
    int row = blockIdx.x * blockDim.x + tid;

    float s = rsum[row];
    unsigned int m = mask[row];
    bool zero   = (s == 0.0f);
    bool tblp   = use_table && !zero && ((m & 3u) == 1u) && (__popc(m) == 2);
    bool fb     = !zero && !tblp;

    // stage fallback weights only if some thread in this block needs them
    if (__syncthreads_or(fb ? 1 : 0)) {
        for (int i = tid; i < 4 * RNNH * RNNH; i += blockDim.x) {
            int gu = i / RNNH, k = i % RNNH;
            int gate = gu / RNNH, u = gu % RNNH;
            float w = Whh[i];
            if      (gate == 0) sW1t[k][u]        = w;   // i
            else if (gate == 2) sW1t[k][RNNH + u] = w;   // g
            else if (gate == 1) sW2t[k][u]        = w;   // f
            else                sW2t[k][RNNH + u] = w;   // o
        }
        if (tid < 4 * RNNH) {
            float a = 0.0f, cc = bih[tid] + bhh[tid];
            for (int k = 0; k < RNNH; k++) {
                float w = Wih[tid * RNNH + k];
                a = fmaf(rW1[k], w, a);
                cc = fmaf(rb1[k], w, cc);
            }
            sA[tid] = a; sC[tid] = cc;
        }
        if (tid < RNNH) sW2r[tid] = rW2[tid];
        if (tid == 0) sb2o = rb2[0];
        __syncthreads();
    }

    if (zero) { out[row] = 0.0f; return; }

    if (tblp) {
        float v0 = out[row];                       // stashed by kernel 1 (pos==0 event)
        float vmin = fdec(vr[0]), vmax = fdec(vr[1]);
        float inv = (float)(TBL - 1) / fmaxf(vmax - vmin, 1e-35f);
        float t = (v0 - vmin) * inv;
        t = fminf(fmaxf(t, 0.0f), (float)(TBL - 1));
        int idx = (int)t; if (idx > TBL - 2) idx = TBL - 2;
        float frac = t - (float)idx;
        float t0 = table[idx], t1 = table[idx + 1];
        out[row] = fmaf(frac, t1 - t0, t0);
        return;
    }

    // ---------- general fallback (verified round-5 path) ----------
    int len = __popc(m);
    const float* vrow = vox + (size_t)row * M_EVC;
    float* myh = &sH[tid * HPAD];

    float c[RNNH];
    float oacc;

    {
        float x0 = (m & 1u) ? vrow[0] : 0.0f;
        oacc = sb2o;
#pragma unroll
        for (int u = 0; u < RNNH; u++) {
            float gi = fmaf(x0, sA[u],            sC[u]);
            float gg = fmaf(x0, sA[u + 2 * RNNH], sC[u + 2 * RNNH]);
            float go = fmaf(x0, sA[u + 3 * RNNH], sC[u + 3 * RNNH]);
            float cn = sigm(gi) * ftanh(gg);
            c[u] = cn;
            float hu = sigm(go) * ftanh(cn);
            myh[u] = hu;
            oacc = fmaf(hu, sW2r[u], oacc);
        }
    }

    for (int j = 1; j < len; j++) {
        float xj = ((m >> j) & 1u) ? vrow[j] : 0.0f;

        float a1[2 * RNNH];
#pragma unroll
        for (int q = 0; q < 5; q++) {
            float4 ai = ((const float4*)sA)[q],      ci = ((const float4*)sC)[q];
            float4 ag = ((const float4*)sA)[10 + q], cg = ((const float4*)sC)[10 + q];
            a1[4 * q + 0] = fmaf(xj, ai.x, ci.x);
            a1[4 * q + 1] = fmaf(xj, ai.y, ci.y);
            a1[4 * q + 2] = fmaf(xj, ai.z, ci.z);
            a1[4 * q + 3] = fmaf(xj, ai.w, ci.w);
            a1[RNNH + 4 * q + 0] = fmaf(xj, ag.x, cg.x);
            a1[RNNH + 4 * q + 1] = fmaf(xj, ag.y, cg.y);
            a1[RNNH + 4 * q + 2] = fmaf(xj, ag.z, cg.z);
            a1[RNNH + 4 * q + 3] = fmaf(xj, ag.w, cg.w);
        }
#pragma unroll 1
        for (int k = 0; k < RNNH; k++) {
            float hk = myh[k];
            const float4* wr = (const float4*)&sW1t[k][0];
#pragma unroll
            for (int q = 0; q < 10; q++) {
                float4 w = wr[q];
                a1[4 * q + 0] = fmaf(hk, w.x, a1[4 * q + 0]);
                a1[4 * q + 1] = fmaf(hk, w.y, a1[4 * q + 1]);
                a1[4 * q + 2] = fmaf(hk, w.z, a1[4 * q + 2]);
                a1[4 * q + 3] = fmaf(hk, w.w, a1[4 * q + 3]);
            }
        }
        float cand[RNNH];
#pragma unroll
        for (int u = 0; u < RNNH; u++) cand[u] = sigm(a1[u]) * ftanh(a1[RNNH + u]);

        float a2[2 * RNNH];
#pragma unroll
        for (int q = 0; q < 5; q++) {
            float4 af = ((const float4*)sA)[5 + q],  cf = ((const float4*)sC)[5 + q];
            float4 ao = ((const float4*)sA)[15 + q], co = ((const float4*)sC)[15 + q];
            a2[4 * q + 0] = fmaf(xj, af.x, cf.x);
            a2[4 * q + 1] = fmaf(xj, af.y, cf.y);
            a2[4 * q + 2] = fmaf(xj, af.z, cf.z);
            a2[4 * q + 3] = fmaf(xj, af.w, cf.w);
            a2[RNNH + 4 * q + 0] = fmaf(xj, ao.x, co.x);
            a2[RNNH + 4 * q + 1] = fmaf(xj, ao.y, co.y);
            a2[RNNH + 4 * q + 2] = fmaf(xj, ao.z, co.z);
            a2[RNNH + 4 * q + 3] = fmaf(xj, ao.w, co.w);
        }
#pragma unroll 1
        for (int k = 0; k < RNNH; k++) {
            float hk = myh[k];
            const float4* wr = (const float4*)&sW2t[k][0];
#pragma unroll
            for (int q = 0; q < 10; q++) {
                float4 w = wr[q];
                a2[4 * q + 0] = fmaf(hk, w.x, a2[4 * q + 0]);
                a2[4 * q + 1] = fmaf(hk, w.y, a2[4 * q + 1]);
                a2[4 * q + 2] = fmaf(hk, w.z, a2[4 * q + 2]);
                a2[4 * q + 3] = fmaf(hk, w.w, a2[4 * q + 3]);
            }
        }

        oacc = sb2o;
#pragma unroll
        for (int u = 0; u < RNNH; u++) {
            float cn = fmaf(sigm(a2[u]), c[u], cand[u]);
            c[u] = cn;
            float hu = sigm(a2[RNNH + u]) * ftanh(cn);
            myh[u] = hu;
            oacc = fmaf(hu, sW2r[u], oacc);
        }
    }

    out[row] = oacc;
}

extern "C" void kernel_launch(void* const* d_in, const int* in_sizes, int n_in,
                              void* d_out, int out_size, void* d_ws, size_t ws_size,
                              hipStream_t stream) {
    const float* ev     = (const float*)d_in[0];
    const float* mlp_W1 = (const float*)d_in[1];
    const float* mlp_b1 = (const float*)d_in[2];
    const float* mlp_W2 = (const float*)d_in[3];
    const float* mlp_b2 = (const float*)d_in[4];
    const float* mlp_W3 = (const float*)d_in[5];
    const float* mlp_b3 = (const float*)d_in[6];
    const float* rnn_W1 = (const float*)d_in[7];
    const float* rnn_b1 = (const float*)d_in[8];
    const float* W_ih   = (const float*)d_in[9];
    const float* W_hh   = (const float*)d_in[10];
    const float* b_ih   = (const float*)d_in[11];
    const float* b_hh   = (const float*)d_in[12];
    const float* rnn_W2 = (const float*)d_in[13];
    const float* rnn_b2 = (const float*)d_in[14];

    int n = in_sizes[0] / 7;
    float* outp = (float*)d_out;

    unsigned char* ws = (unsigned char*)d_ws;
    unsigned int* mask = (unsigned int*)ws;                        // ROWS u32
    float*        rsum = (float*)(ws + (size_t)ROWS * 4);          // ROWS f32
    float*        vox  = (float*)(ws + (size_t)ROWS * 8);          // ROWS*32 f32
    size_t base_need   = (size_t)ROWS * 8 + (size_t)ROWS * M_EVC * 4;
    size_t tbl_need    = base_need + (size_t)TBL * 4 + 8;
    int use_table      = (ws_size >= tbl_need) ? 1 : 0;
    float*    table    = (float*)(ws + base_need);
    unsigned* vrange   = (unsigned*)(ws + base_need + (size_t)TBL * 4);

    hipMemsetAsync(mask, 0, (size_t)ROWS * 8, stream);
    if (use_table) init_range<<<1, 1, 0, stream>>>(vrange);

    int blk = 256;
    int grid1 = (n + blk - 1) / blk;
    ev_mlp_scatter<<<grid1, blk, 0, stream>>>(ev, n, mlp_W1, mlp_b1, mlp_W2, mlp_b2,
                                              mlp_W3, mlp_b3, vox, mask, rsum,
                                              outp, vrange, use_table);

    if (use_table)
        build_table<<<TBL / blk, blk, 0, stream>>>(rnn_W1, rnn_b1, W_ih, W_hh,
                                                   b_ih, b_hh, rnn_W2, rnn_b2,
                                                   vrange, table);

    int grid2 = (ROWS + blk - 1) / blk;   // 4050
    row_out<<<grid2, blk, 0, stream>>>(mask, rsum, vox, rnn_W1, rnn_b1, W_ih, W_hh,
                                       b_ih, b_hh, rnn_W2, rnn_b2,
                                       table, vrange, use_table, outp);
}

// Round 7
// 156.664 us; speedup vs baseline: 5.0436x; 5.0436x over previous
//
#include <hip/hip_runtime.h>
#include <math.h>

#define HH 180
#define WW 240
#define T_AGGC 3
#define NBC 4
#define BBC (NBC * T_AGGC)          // 12
#define M_EVC 32
#define ROWS (BBC * 2 * HH * WW)    // 1,036,800
#define MLPH 20
#define RNNH 20
#define LRELU_SLOPE 0.1f
#define HPAD 21                     // per-thread h stride in LDS (fallback path)
#define TBL 65536                   // table entries over t in [-1,1]

__device__ __forceinline__ float lrelu(float x) { return x > 0.0f ? x : LRELU_SLOPE * x; }
__device__ __forceinline__ float sigm(float x)  { return 1.0f / (1.0f + __expf(-x)); }
__device__ __forceinline__ float ftanh(float x) { return 1.0f - 2.0f / (__expf(2.0f * x) + 1.0f); }

// ---------------- Table builder: mlp_tbl[i] = MLP(t_i), g_tbl[i] = LSTM-out(MLP(t_i)) ----------------
// t_i = -1 + 2*i/(TBL-1). One launch, 256 blocks.
__global__ __launch_bounds__(256) void build_tables(
    const float* __restrict__ W1, const float* __restrict__ b1,
    const float* __restrict__ W2, const float* __restrict__ b2,
    const float* __restrict__ W3, const float* __restrict__ b3,
    const float* __restrict__ rW1, const float* __restrict__ rb1,
    const float* __restrict__ Wih, const float* __restrict__ Whh,
    const float* __restrict__ bih, const float* __restrict__ bhh,
    const float* __restrict__ rW2, const float* __restrict__ rb2,
    float* __restrict__ mlp_tbl, float* __restrict__ g_tbl,
    int build_mlp, int build_g)
{
    __shared__ __align__(16) float sW2m[MLPH * MLPH];
    __shared__ float sW1m[MLPH], sb1m[MLPH], sb2m[MLPH], sW3m[MLPH];
    __shared__ float sb3m;
    __shared__ __align__(16) float sW[4 * RNNH * RNNH];   // Whh row-major
    __shared__ __align__(16) float sA[4 * RNNH], sC[4 * RNNH];
    __shared__ float sW2r[RNNH];
    __shared__ float sb2o;

    int tid = threadIdx.x;
    for (int i = tid; i < MLPH * MLPH; i += blockDim.x) sW2m[i] = W2[i];
    for (int i = tid; i < 4 * RNNH * RNNH; i += blockDim.x) sW[i] = Whh[i];
    if (tid < MLPH) { sW1m[tid] = W1[tid]; sb1m[tid] = b1[tid]; sb2m[tid] = b2[tid]; sW3m[tid] = W3[tid]; }
    if (tid < 4 * RNNH) {
        float a = 0.0f, cc = bih[tid] + bhh[tid];
        for (int k = 0; k < RNNH; k++) {
            float w = Wih[tid * RNNH + k];
            a = fmaf(rW1[k], w, a);
            cc = fmaf(rb1[k], w, cc);
        }
        sA[tid] = a; sC[tid] = cc;
    }
    if (tid < RNNH) sW2r[tid] = rW2[tid];
    if (tid == 0) { sb3m = b3[0]; sb2o = rb2[0]; }
    __syncthreads();

    int i = blockIdx.x * blockDim.x + tid;
    float t = -1.0f + (2.0f / (TBL - 1)) * (float)i;

    // exact MLP(t)
    float h1[MLPH];
#pragma unroll
    for (int k = 0; k < MLPH; k++) h1[k] = lrelu(fmaf(t, sW1m[k], sb1m[k]));
    float val = sb3m;
#pragma unroll
    for (int j = 0; j < MLPH; j++) {
        float a = sb2m[j];
        const float4* wr = (const float4*)&sW2m[j * MLPH];
#pragma unroll
        for (int k4 = 0; k4 < MLPH / 4; k4++) {
            float4 w = wr[k4];
            a = fmaf(h1[k4 * 4 + 0], w.x, a);
            a = fmaf(h1[k4 * 4 + 1], w.y, a);
            a = fmaf(h1[k4 * 4 + 2], w.z, a);
            a = fmaf(h1[k4 * 4 + 3], w.w, a);
        }
        val = fmaf(lrelu(a), sW3m[j], val);
    }
    if (build_mlp) mlp_tbl[i] = val;

    if (!build_g) return;

    // LSTM step 0 (h=c=0) with x=val
    float h0[RNNH], c1[RNNH];
#pragma unroll
    for (int u = 0; u < RNNH; u++) {
        float gi = fmaf(val, sA[u],            sC[u]);
        float gg = fmaf(val, sA[u + 2 * RNNH], sC[u + 2 * RNNH]);
        float go = fmaf(val, sA[u + 3 * RNNH], sC[u + 3 * RNNH]);
        float cn = sigm(gi) * ftanh(gg);
        c1[u] = cn;
        h0[u] = sigm(go) * ftanh(cn);
    }
    // step 1 with x=0: gates = C + h0 @ Whh^T ; then projection
    float oacc = sb2o;
#pragma unroll
    for (int u = 0; u < RNNH; u++) {
        float gi = sC[u], gf = sC[u + RNNH], gg = sC[u + 2 * RNNH], go = sC[u + 3 * RNNH];
        const float4* wi = (const float4*)&sW[u * RNNH];
        const float4* wf = (const float4*)&sW[(u + RNNH) * RNNH];
        const float4* wg = (const float4*)&sW[(u + 2 * RNNH) * RNNH];
        const float4* wo = (const float4*)&sW[(u + 3 * RNNH) * RNNH];
#pragma unroll
        for (int q = 0; q < 5; q++) {
            float4 a = wi[q], b = wf[q], cq = wg[q], d = wo[q];
            gi = fmaf(h0[4*q+0], a.x, gi); gi = fmaf(h0[4*q+1], a.y, gi);
            gi = fmaf(h0[4*q+2], a.z, gi); gi = fmaf(h0[4*q+3], a.w, gi);
            gf = fmaf(h0[4*q+0], b.x, gf); gf = fmaf(h0[4*q+1], b.y, gf);
            gf = fmaf(h0[4*q+2], b.z, gf); gf = fmaf(h0[4*q+3], b.w, gf);
            gg = fmaf(h0[4*q+0], cq.x, gg); gg = fmaf(h0[4*q+1], cq.y, gg);
            gg = fmaf(h0[4*q+2], cq.z, gg); gg = fmaf(h0[4*q+3], cq.w, gg);
            go = fmaf(h0[4*q+0], d.x, go); go = fmaf(h0[4*q+1], d.y, go);
            go = fmaf(h0[4*q+2], d.z, go); go = fmaf(h0[4*q+3], d.w, go);
        }
        float c2 = fmaf(sigm(gf), c1[u], sigm(gi) * ftanh(gg));
        oacc = fmaf(sigm(go) * ftanh(c2), sW2r[u], oacc);
    }
    g_tbl[i] = oacc;
}

// ---------------- Kernel 1: per-event value (table or exact MLP) + scatter ----------------
__global__ __launch_bounds__(256) void ev_mlp_scatter(
    const float* __restrict__ ev, int n,
    const float* __restrict__ W1, const float* __restrict__ b1,
    const float* __restrict__ W2, const float* __restrict__ b2,
    const float* __restrict__ W3, const float* __restrict__ b3,
    const float* __restrict__ mlp_tbl, int use_mlp_tbl,
    float* __restrict__ vox, unsigned int* __restrict__ mask,
    float* __restrict__ rsum,
    float* __restrict__ t0stash,           // = d_out (contiguous by row)
    float* __restrict__ v0b, int compact0)
{
    __shared__ __align__(16) float sW2[MLPH * MLPH];
    __shared__ float sW1[MLPH], sb1[MLPH], sb2[MLPH], sW3[MLPH];
    __shared__ float sb3;
    int tid = threadIdx.x;
    if (!use_mlp_tbl) {
        for (int i = tid; i < MLPH * MLPH; i += blockDim.x) sW2[i] = W2[i];
        if (tid < MLPH) { sW1[tid] = W1[tid]; sb1[tid] = b1[tid]; sb2[tid] = b2[tid]; sW3[tid] = W3[tid]; }
        if (tid == 0) sb3 = b3[0];
        __syncthreads();
    }

    int i = blockIdx.x * blockDim.x + tid;
    if (i >= n) return;
    const float* e = ev + (size_t)i * 7;
    float t = e[3];

    float val;
    if (use_mlp_tbl) {
        float x = (t + 1.0f) * (0.5f * (TBL - 1));
        x = fminf(fmaxf(x, 0.0f), (float)(TBL - 1));
        int idx = (int)x; if (idx > TBL - 2) idx = TBL - 2;
        float frac = x - (float)idx;
        float t0v = mlp_tbl[idx], t1v = mlp_tbl[idx + 1];
        val = fmaf(frac, t1v - t0v, t0v);
    } else {
        float h1[MLPH];
#pragma unroll
        for (int k = 0; k < MLPH; k++) h1[k] = lrelu(fmaf(t, sW1[k], sb1[k]));
        val = sb3;
#pragma unroll
        for (int j = 0; j < MLPH; j++) {
            float a = sb2[j];
            const float4* wr = (const float4*)&sW2[j * MLPH];
#pragma unroll
            for (int k4 = 0; k4 < MLPH / 4; k4++) {
                float4 w = wr[k4];
                a = fmaf(h1[k4 * 4 + 0], w.x, a);
                a = fmaf(h1[k4 * 4 + 1], w.y, a);
                a = fmaf(h1[k4 * 4 + 2], w.z, a);
                a = fmaf(h1[k4 * 4 + 3], w.w, a);
            }
            val = fmaf(lrelu(a), sW3[j], val);
        }
    }

    int xi = (int)e[0], yi = (int)e[1], pi = (int)e[2];
    int ipi = (int)e[4], ti = (int)e[5], bi = (int)e[6];
    int row = xi + WW * yi + WW * HH * pi + 2 * WW * HH * (bi * T_AGGC + ti);
    int pos = ipi - 1;

    if (pos == 0) {
        t0stash[row] = t;                              // contiguous (row = i/2 here)
        if (compact0) v0b[row] = val;                  // contiguous value stash
        else          vox[(size_t)row * M_EVC] = val;
    } else {
        vox[(size_t)row * M_EVC + pos] = val;
    }
    if (val != 0.0f) {                                 // matches (vox != 0) semantics
        atomicOr(&mask[row], 1u << pos);
        atomicAdd(&rsum[row], val);
    }
}

// ---------------- Kernel 2: per-row output (table fast path + general LSTM fallback) ----------------
__global__ __launch_bounds__(256) void row_out(
    const unsigned int* __restrict__ mask, const float* __restrict__ rsum,
    const float* __restrict__ vox, const float* __restrict__ v0b, int compact0,
    const float* __restrict__ rW1, const float* __restrict__ rb1,
    const float* __restrict__ Wih, const float* __restrict__ Whh,
    const float* __restrict__ bih, const float* __restrict__ bhh,
    const float* __restrict__ rW2, const float* __restrict__ rb2,
    const float* __restrict__ g_tbl, int use_table,
    float* __restrict__ out)
{
    __shared__ __align__(16) float sW1t[RNNH][2 * RNNH];  // [k][0..19]=i, [20..39]=g
    __shared__ __align__(16) float sW2t[RNNH][2 * RNNH];  // [k][0..19]=f, [20..39]=o
    __shared__ __align__(16) float sA[4 * RNNH], sC[4 * RNNH];
    __shared__ float sW2r[RNNH];
    __shared__ float sb2o;
    __shared__ float sH[256 * HPAD];

    int tid = threadIdx.x;
    int row = blockIdx.x * blockDim.x + tid;

    float s = rsum[row];
    unsigned int m = mask[row];
    bool zero = (s == 0.0f);
    bool tblp = use_table && !zero && ((m & 3u) == 1u) && (__popc(m) == 2);
    bool fb   = !zero && !tblp;

    if (__syncthreads_or(fb ? 1 : 0)) {
        for (int i = tid; i < 4 * RNNH * RNNH; i += blockDim.x) {
            int gu = i / RNNH, k = i % RNNH;
            int gate = gu / RNNH, u = gu % RNNH;
            float w = Whh[i];
            if      (gate == 0) sW1t[k][u]        = w;
            else if (gate == 2) sW1t[k][RNNH + u] = w;
            else if (gate == 1) sW2t[k][u]        = w;
            else                sW2t[k][RNNH + u] = w;
        }
        if (tid < 4 * RNNH) {
            float a = 0.0f, cc = bih[tid] + bhh[tid];
            for (int k = 0; k < RNNH; k++) {
                float w = Wih[tid * RNNH + k];
                a = fmaf(rW1[k], w, a);
                cc = fmaf(rb1[k], w, cc);
            }
            sA[tid] = a; sC[tid] = cc;
        }
        if (tid < RNNH) sW2r[tid] = rW2[tid];
        if (tid == 0) sb2o = rb2[0];
        __syncthreads();
    }

    if (zero) { out[row] = 0.0f; return; }

    if (tblp) {
        float t0 = out[row];                           // t stashed by kernel 1
        float x = (t0 + 1.0f) * (0.5f * (TBL - 1));
        x = fminf(fmaxf(x, 0.0f), (float)(TBL - 1));
        int idx = (int)x; if (idx > TBL - 2) idx = TBL - 2;
        float frac = x - (float)idx;
        float t0v = g_tbl[idx], t1v = g_tbl[idx + 1];
        out[row] = fmaf(frac, t1v - t0v, t0v);
        return;
    }

    // ---------- general fallback (verified round-5 path) ----------
    int len = __popc(m);
    const float* vrow = vox + (size_t)row * M_EVC;
    float* myh = &sH[tid * HPAD];

    float c[RNNH];
    float oacc;

    {
        float x0 = (m & 1u) ? (compact0 ? v0b[row] : vrow[0]) : 0.0f;
        oacc = sb2o;
#pragma unroll
        for (int u = 0; u < RNNH; u++) {
            float gi = fmaf(x0, sA[u],            sC[u]);
            float gg = fmaf(x0, sA[u + 2 * RNNH], sC[u + 2 * RNNH]);
            float go = fmaf(x0, sA[u + 3 * RNNH], sC[u + 3 * RNNH]);
            float cn = sigm(gi) * ftanh(gg);
            c[u] = cn;
            float hu = sigm(go) * ftanh(cn);
            myh[u] = hu;
            oacc = fmaf(hu, sW2r[u], oacc);
        }
    }

    for (int j = 1; j < len; j++) {
        float xj = ((m >> j) & 1u) ? vrow[j] : 0.0f;

        float a1[2 * RNNH];
#pragma unroll
        for (int q = 0; q < 5; q++) {
            float4 ai = ((const float4*)sA)[q],      ci = ((const float4*)sC)[q];
            float4 ag = ((const float4*)sA)[10 + q], cg = ((const float4*)sC)[10 + q];
            a1[4 * q + 0] = fmaf(xj, ai.x, ci.x);
            a1[4 * q + 1] = fmaf(xj, ai.y, ci.y);
            a1[4 * q + 2] = fmaf(xj, ai.z, ci.z);
            a1[4 * q + 3] = fmaf(xj, ai.w, ci.w);
            a1[RNNH + 4 * q + 0] = fmaf(xj, ag.x, cg.x);
            a1[RNNH + 4 * q + 1] = fmaf(xj, ag.y, cg.y);
            a1[RNNH + 4 * q + 2] = fmaf(xj, ag.z, cg.z);
            a1[RNNH + 4 * q + 3] = fmaf(xj, ag.w, cg.w);
        }
#pragma unroll 1
        for (int k = 0; k < RNNH; k++) {
            float hk = myh[k];
            const float4* wr = (const float4*)&sW1t[k][0];
#pragma unroll
            for (int q = 0; q < 10; q++) {
                float4 w = wr[q];
                a1[4 * q + 0] = fmaf(hk, w.x, a1[4 * q + 0]);
                a1[4 * q + 1] = fmaf(hk, w.y, a1[4 * q + 1]);
                a1[4 * q + 2] = fmaf(hk, w.z, a1[4 * q + 2]);
                a1[4 * q + 3] = fmaf(hk, w.w, a1[4 * q + 3]);
            }
        }
        float cand[RNNH];
#pragma unroll
        for (int u = 0; u < RNNH; u++) cand[u] = sigm(a1[u]) * ftanh(a1[RNNH + u]);

        float a2[2 * RNNH];
#pragma unroll
        for (int q = 0; q < 5; q++) {
            float4 af = ((const float4*)sA)[5 + q],  cf = ((const float4*)sC)[5 + q];
            float4 ao = ((const float4*)sA)[15 + q], co = ((const float4*)sC)[15 + q];
            a2[4 * q + 0] = fmaf(xj, af.x, cf.x);
            a2[4 * q + 1] = fmaf(xj, af.y, cf.y);
            a2[4 * q + 2] = fmaf(xj, af.z, cf.z);
            a2[4 * q + 3] = fmaf(xj, af.w, cf.w);
            a2[RNNH + 4 * q + 0] = fmaf(xj, ao.x, co.x);
            a2[RNNH + 4 * q + 1] = fmaf(xj, ao.y, co.y);
            a2[RNNH + 4 * q + 2] = fmaf(xj, ao.z, co.z);
            a2[RNNH + 4 * q + 3] = fmaf(xj, ao.w, co.w);
        }
#pragma unroll 1
        for (int k = 0; k < RNNH; k++) {
            float hk = myh[k];
            const float4* wr = (const float4*)&sW2t[k][0];
#pragma unroll
            for (int q = 0; q < 10; q++) {
                float4 w = wr[q];
                a2[4 * q + 0] = fmaf(hk, w.x, a2[4 * q + 0]);
                a2[4 * q + 1] = fmaf(hk, w.y, a2[4 * q + 1]);
                a2[4 * q + 2] = fmaf(hk, w.z, a2[4 * q + 2]);
                a2[4 * q + 3] = fmaf(hk, w.w, a2[4 * q + 3]);
            }
        }

        oacc = sb2o;
#pragma unroll
        for (int u = 0; u < RNNH; u++) {
            float cn = fmaf(sigm(a2[u]), c[u], cand[u]);
            c[u] = cn;
            float hu = sigm(a2[RNNH + u]) * ftanh(cn);
            myh[u] = hu;
            oacc = fmaf(hu, sW2r[u], oacc);
        }
    }

    out[row] = oacc;
}

extern "C" void kernel_launch(void* const* d_in, const int* in_sizes, int n_in,
                              void* d_out, int out_size, void* d_ws, size_t ws_size,
                              hipStream_t stream) {
    const float* ev     = (const float*)d_in[0];
    const float* mlp_W1 = (const float*)d_in[1];
    const float* mlp_b1 = (const float*)d_in[2];
    const float* mlp_W2 = (const float*)d_in[3];
    const float* mlp_b2 = (const float*)d_in[4];
    const float* mlp_W3 = (const float*)d_in[5];
    const float* mlp_b3 = (const float*)d_in[6];
    const float* rnn_W1 = (const float*)d_in[7];
    const float* rnn_b1 = (const float*)d_in[8];
    const float* W_ih   = (const float*)d_in[9];
    const float* W_hh   = (const float*)d_in[10];
    const float* b_ih   = (const float*)d_in[11];
    const float* b_hh   = (const float*)d_in[12];
    const float* rnn_W2 = (const float*)d_in[13];
    const float* rnn_b2 = (const float*)d_in[14];

    int n = in_sizes[0] / 7;
    float* outp = (float*)d_out;

    unsigned char* ws = (unsigned char*)d_ws;
    size_t off = 0;
    unsigned int* mask = (unsigned int*)(ws + off); off += (size_t)ROWS * 4;
    float*        rsum = (float*)(ws + off);        off += (size_t)ROWS * 4;
    float*        vox  = (float*)(ws + off);        off += (size_t)ROWS * M_EVC * 4;
    size_t base_need = off;
    float* g_tbl   = (float*)(ws + off); off += (size_t)TBL * 4;
    size_t gtbl_need = off;
    float* mlp_tbl = (float*)(ws + off); off += (size_t)TBL * 4;
    size_t mtbl_need = off;
    float* v0b     = (float*)(ws + off); off += (size_t)ROWS * 4;
    size_t v0b_need = off;

    (void)base_need;
    int use_table   = (ws_size >= gtbl_need) ? 1 : 0;
    int use_mlp_tbl = (ws_size >= mtbl_need) ? 1 : 0;
    int compact0    = (ws_size >= v0b_need)  ? 1 : 0;

    hipMemsetAsync(mask, 0, (size_t)ROWS * 8, stream);

    int blk = 256;
    if (use_table || use_mlp_tbl)
        build_tables<<<TBL / blk, blk, 0, stream>>>(mlp_W1, mlp_b1, mlp_W2, mlp_b2,
                                                    mlp_W3, mlp_b3,
                                                    rnn_W1, rnn_b1, W_ih, W_hh,
                                                    b_ih, b_hh, rnn_W2, rnn_b2,
                                                    mlp_tbl, g_tbl, use_mlp_tbl, use_table);

    int grid1 = (n + blk - 1) / blk;
    ev_mlp_scatter<<<grid1, blk, 0, stream>>>(ev, n, mlp_W1, mlp_b1, mlp_W2, mlp_b2,
                                              mlp_W3, mlp_b3, mlp_tbl, use_mlp_tbl,
                                              vox, mask, rsum, outp, v0b, compact0);

    int grid2 = (ROWS + blk - 1) / blk;   // 4050
    row_out<<<grid2, blk, 0, stream>>>(mask, rsum, vox, v0b, compact0,
                                       rnn_W1, rnn_b1, W_ih, W_hh,
                                       b_ih, b_hh, rnn_W2, rnn_b2,
                                       g_tbl, use_table, outp);
}